// Round 9
// baseline (207.212 us; speedup 1.0000x reference)
//
#include <hip/hip_runtime.h>

// Problem constants: B=2, S=2048, D=1024, H=16, HD=64
#define BB 2
#define SS 2048
#define DD 1024
#define HH 16
#define HD 64
#define MM (BB*SS)   // 4096 rows

typedef __bf16 bf16x8 __attribute__((ext_vector_type(8)));
typedef short  s16x4  __attribute__((ext_vector_type(4)));
typedef float  f32x4  __attribute__((ext_vector_type(4)));

#ifndef __has_builtin
#define __has_builtin(x) 0
#endif

__device__ __forceinline__ unsigned short f2bf(float f) {
    unsigned int u = __float_as_uint(f);
    u = (u + 0x7fffu + ((u >> 16) & 1u)) >> 16;  // RNE
    return (unsigned short)u;
}
__device__ __forceinline__ unsigned int pack2(float a, float b) {
    return (unsigned int)f2bf(a) | ((unsigned int)f2bf(b) << 16);
}
// fast pack (round-half-up): 2 adds + 1 v_perm
__device__ __forceinline__ unsigned int pack2_fast(float a, float b) {
#if __has_builtin(__builtin_amdgcn_perm)
    return __builtin_amdgcn_perm(__float_as_uint(b) + 0x8000u,
                                 __float_as_uint(a) + 0x8000u, 0x07060302u);
#else
    return ((__float_as_uint(a) + 0x8000u) >> 16) |
           ((__float_as_uint(b) + 0x8000u) & 0xffff0000u);
#endif
}

// async global->LDS, 16B per lane; LDS dest = wave-uniform base + lane*16
__device__ __forceinline__ void gload_lds16(const unsigned short* g, unsigned short* l) {
    __builtin_amdgcn_global_load_lds(
        (const __attribute__((address_space(1))) void*)g,
        (__attribute__((address_space(3))) void*)l, 16, 0, 0);
}

// ---------------- fused prep: cast x -> bf16, transpose W -> bf16 [n][k] ----------------
// blocks [0,2048): cast_x (8 elems/thread).  blocks [2048,6144): W transpose.
__global__ __launch_bounds__(256) void prep_kernel(const float* __restrict__ x,
                                                   const float* __restrict__ Wq,
                                                   const float* __restrict__ Wk,
                                                   const float* __restrict__ Wv,
                                                   const float* __restrict__ Wo,
                                                   unsigned short* __restrict__ Xb,
                                                   unsigned short* __restrict__ Wqkvt,
                                                   unsigned short* __restrict__ Wot) {
    __shared__ float tile[32][33];
    const int bx = blockIdx.x;
    const int t = threadIdx.x;
    if (bx < 2048) {
        int gid = bx * 256 + t;
        int i = gid * 8;
        float4 a = *(const float4*)(x + i);
        float4 b = *(const float4*)(x + i + 4);
        uint4 o;
        o.x = pack2(a.x, a.y); o.y = pack2(a.z, a.w);
        o.z = pack2(b.x, b.y); o.w = pack2(b.z, b.w);
        ((uint4*)Xb)[gid] = o;
        return;
    }
    int pb = bx - 2048;
    int p = pb >> 10, rem = pb & 1023;
    int bxx = rem & 31, byy = rem >> 5;
    const float* src = (p == 0) ? Wq : (p == 1) ? Wk : (p == 2) ? Wv : Wo;
    unsigned short* dst = (p == 3) ? Wot : (Wqkvt + (size_t)p * DD * DD);
    int tx = t & 31, ty = t >> 5;
    int n = bxx * 32 + tx;
#pragma unroll
    for (int i = 0; i < 4; ++i) {
        int k = byy * 32 + ty + i * 8;
        tile[ty + i * 8][tx] = src[k * DD + n];
    }
    __syncthreads();
#pragma unroll
    for (int i = 0; i < 4; ++i) {
        int n2 = bxx * 32 + ty + i * 8;
        int k2 = byy * 32 + tx;
        dst[n2 * DD + k2] = f2bf(tile[tx][ty + i * 8]);
    }
}

// ============ 128x128-tile GEMM K-loop, global_load_lds staging, xor-swizzled ============
#define GEMM_K_LOOP(Aglob, Bglob)                                                 \
    __shared__ unsigned short smem[128 * 132];                                    \
    unsigned short (*As)[64]  = (unsigned short(*)[64])smem;                      \
    unsigned short (*Bs)[64]  = (unsigned short(*)[64])(smem + 128 * 64);         \
    unsigned short (*Es)[132] = (unsigned short(*)[132])smem;                     \
    const int n0 = blockIdx.x * 128, m0 = blockIdx.y * 128;                       \
    const int t = threadIdx.x;                                                    \
    const int wave = t >> 6, lane = t & 63;                                       \
    const int wm = wave >> 1, wn = wave & 1;                                      \
    const int l15 = lane & 15, quad = lane >> 4;                                  \
    const int lr = lane >> 3, lg = (lane & 7);                                    \
    const int lc = (lg ^ lr) * 8;   /* swizzled source granule */                 \
    f32x4 acc[4][4];                                                              \
    _Pragma("unroll") for (int i = 0; i < 4; ++i)                                 \
        _Pragma("unroll") for (int j = 0; j < 4; ++j) acc[i][j] = f32x4{0,0,0,0}; \
    for (int kt = 0; kt < 16; ++kt) {                                             \
        if (kt) __syncthreads();                                                  \
        _Pragma("unroll") for (int i = 0; i < 4; ++i) {                           \
            int row = wave * 32 + i * 8;                                          \
            gload_lds16(Aglob + (size_t)(m0 + row + lr) * DD + kt * 64 + lc, &As[row][0]); \
            gload_lds16(Bglob + (size_t)(n0 + row + lr) * DD + kt * 64 + lc, &Bs[row][0]); \
        }                                                                         \
        __syncthreads();                                                          \
        _Pragma("unroll") for (int kh = 0; kh < 2; ++kh) {                        \
            bf16x8 af[4], bfr[4];                                                 \
            _Pragma("unroll") for (int s = 0; s < 4; ++s)                         \
                af[s] = *(const bf16x8*)&As[wm * 64 + s * 16 + l15][((kh * 4 + quad) ^ (l15 & 7)) * 8]; \
            _Pragma("unroll") for (int s = 0; s < 4; ++s)                         \
                bfr[s] = *(const bf16x8*)&Bs[wn * 64 + s * 16 + l15][((kh * 4 + quad) ^ (l15 & 7)) * 8]; \
            _Pragma("unroll") for (int i = 0; i < 4; ++i)                         \
                _Pragma("unroll") for (int j = 0; j < 4; ++j)                     \
                    acc[i][j] = __builtin_amdgcn_mfma_f32_16x16x32_bf16(af[i], bfr[j], acc[i][j], 0, 0, 0); \
        }                                                                         \
    }                                                                             \
    __syncthreads();   /* K-loop done; smem reusable */

// ---------------- QKV fused GEMM; LDS-transpose epilogue; Q pre-scaled ----------------
__global__ __launch_bounds__(256) void qkv_gemm_kernel(const unsigned short* __restrict__ Xb,
                                                       const unsigned short* __restrict__ Wt,
                                                       unsigned short* __restrict__ Qg,
                                                       unsigned short* __restrict__ Kg,
                                                       unsigned short* __restrict__ Vt) {
    GEMM_K_LOOP(Xb, Wt)
    const int p = n0 >> 10;   // projection uniform per block
    const float qs = (p == 0) ? 0.18033688011112042f : 1.0f;  // log2(e)/sqrt(HD) folded into Q
    if (p < 2) {
#pragma unroll
        for (int sm = 0; sm < 4; ++sm)
#pragma unroll
            for (int sn = 0; sn < 4; ++sn)
#pragma unroll
                for (int i = 0; i < 4; ++i)
                    Es[wm * 64 + sm * 16 + quad * 4 + i][wn * 64 + sn * 16 + l15] = f2bf(acc[sm][sn][i] * qs);
    } else {
#pragma unroll
        for (int sm = 0; sm < 4; ++sm)
#pragma unroll
            for (int sn = 0; sn < 4; ++sn)
#pragma unroll
                for (int i = 0; i < 4; ++i)
                    Es[wn * 64 + sn * 16 + l15][wm * 64 + sm * 16 + quad * 4 + i] = f2bf(acc[sm][sn][i]);
    }
    __syncthreads();
    const int h0 = (n0 & 1023) >> 6;
    if (p < 2) {
        unsigned short* dst0 = p ? Kg : Qg;
        int ml = t >> 1, seg = t & 1;
        int gm = m0 + ml, b = gm >> 11, s = gm & 2047;
        unsigned short* dptr = dst0 + ((size_t)(b * HH + h0 + seg) * SS + s) * HD;
#pragma unroll
        for (int j = 0; j < 8; ++j)
            *(uint4*)(dptr + j * 8) = *(const uint4*)&Es[ml][seg * 64 + j * 8];
    } else {
        int nl = t >> 1, mh = t & 1;
        int h = h0 + (nl >> 6), hd = nl & 63;
        int b = m0 >> 11, s0 = (m0 & 2047) + mh * 64;
        unsigned short* dptr = Vt + ((size_t)(b * HH + h) * HD + hd) * SS + s0;
#pragma unroll
        for (int j = 0; j < 8; ++j)
            *(uint4*)(dptr + j * 8) = *(const uint4*)&Es[nl][mh * 64 + j * 8];
    }
}

// ---------------- Output projection: out = Ctx @ Wo + bo (fp32 out) ----------------
__global__ __launch_bounds__(256) void out_gemm_kernel(const unsigned short* __restrict__ Ctxb,
                                                       const unsigned short* __restrict__ Wot,
                                                       const float* __restrict__ bo,
                                                       float* __restrict__ out) {
    GEMM_K_LOOP(Ctxb, Wot)
    (void)Es;
#pragma unroll
    for (int sn = 0; sn < 4; ++sn) {
        int gn = n0 + wn * 64 + sn * 16 + l15;
        float bias = bo[gn];
#pragma unroll
        for (int sm = 0; sm < 4; ++sm)
#pragma unroll
            for (int i = 0; i < 4; ++i) {
                int gm = m0 + wm * 64 + sm * 16 + quad * 4 + i;
                out[(size_t)gm * DD + gn] = acc[sm][sn][i] + bias;
            }
    }
}

// ---------------- MFMA flash attention, causal, balanced tile-pairing ----------------
// Block = (bh, pair i): processes q-tiles qtA=i and qtB=31-i (64 queries each) with ONE
// shared 128-key double-buffered K/V stream (A's key range is a prefix of B's).
// Every block runs exactly ceil((i+1)/2) + ceil((32-i)/2) = 17 k-iters -> perfectly
// uniform grid of 512 blocks = 2/CU, all co-resident, no drain/tail.
// Wave frag qf0 = 16 queries of A, qf1 = 16 of B. l via ones-MFMA (in-lane epilogue).
__global__ __launch_bounds__(256) void attn_kernel(const unsigned short* __restrict__ Qg,
                                                   const unsigned short* __restrict__ Kg,
                                                   const unsigned short* __restrict__ Vt,
                                                   unsigned short* __restrict__ Ctxb) {
    __shared__ unsigned short Ks[2][128][64];
    __shared__ unsigned short Vs[2][64][128];

    const int bh = blockIdx.x;
    const int pi = blockIdx.y;           // pair index 0..15
    const int t = threadIdx.x;
    const int wave = t >> 6, lane = t & 63;
    const int l15 = lane & 15, quad = lane >> 4;
    const int q0A = pi * 64;
    const int q0B = (31 - pi) * 64;
    const int aIters = (pi + 2) >> 1;          // ceil((pi+1)/2)
    const int bIters = (33 - pi) >> 1;         // ceil((32-pi)/2)
    const int b = bh >> 4, h = bh & 15;

    const unsigned short* Qb = Qg + (size_t)bh * SS * HD;
    const unsigned short* Kb = Kg + (size_t)bh * SS * HD;
    const unsigned short* Vb = Vt + (size_t)bh * HD * SS;

    // Q fragments (B operand): qf0 from tile A, qf1 from tile B
    const int qrow0 = q0A + wave * 16 + l15;
    const int qrow1 = q0B + wave * 16 + l15;
    const int qA_hi = q0A + wave * 16 + 15;
    const int qB_hi = q0B + wave * 16 + 15;
    bf16x8 bq[2][2];
#pragma unroll
    for (int hh = 0; hh < 2; ++hh) {
        bq[0][hh] = *(const bf16x8*)(Qb + (size_t)qrow0 * HD + hh * 32 + quad * 8);
        bq[1][hh] = *(const bf16x8*)(Qb + (size_t)qrow1 * HD + hh * 32 + quad * 8);
    }

    // DMA lane decomposition + swizzled source addresses
    const int rloc = lane >> 3, pcl = lane & 7;   // K: 8 rows x 8 granules (16B)
    const int vrl = lane >> 4, vgc = lane & 15;   // V: 4 rows x 16 granules (16B)
    const unsigned short* ksrc[4];
    const unsigned short* vsrc[4];
#pragma unroll
    for (int j = 0; j < 4; ++j) {
        int krow = (wave * 4 + j) * 8 + rloc;
        ksrc[j] = Kb + (size_t)krow * HD + (pcl ^ rloc) * 8;
        int vrow = wave * 16 + j * 4 + vrl;
        vsrc[j] = Vb + (size_t)vrow * SS + (vgc ^ (vrow & 15)) * 8;
    }

    f32x4 acc[2][4];
#pragma unroll
    for (int qf = 0; qf < 2; ++qf)
#pragma unroll
        for (int db = 0; db < 4; ++db) acc[qf][db] = f32x4{0,0,0,0};
    f32x4 accl[2] = {f32x4{0,0,0,0}, f32x4{0,0,0,0}};
    const s16x4 ones = {(short)0x3F80, (short)0x3F80, (short)0x3F80, (short)0x3F80};

    // prologue: tile 0 -> buf 0
#pragma unroll
    for (int j = 0; j < 4; ++j) {
        gload_lds16(ksrc[j], &Ks[0][(wave * 4 + j) * 8][0]);
        gload_lds16(vsrc[j], &Vs[0][wave * 16 + j * 4][0]);
    }
    __syncthreads();

    for (int kt = 0; kt < bIters; ++kt) {
        const int buf = kt & 1;
        const int k0 = kt * 128;
        if (kt + 1 < bIters) {
            const int nb = buf ^ 1;
#pragma unroll
            for (int j = 0; j < 4; ++j) {
                gload_lds16(ksrc[j] + (size_t)(kt + 1) * 128 * HD, &Ks[nb][(wave * 4 + j) * 8][0]);
                gload_lds16(vsrc[j] + (kt + 1) * 128,              &Vs[nb][wave * 16 + j * 4][0]);
            }
        }

        const bool diagA = (kt == aIters - 1);
        const bool diagB = (kt == bIters - 1);
        const bool inA = (kt < aIters);
#pragma unroll
        for (int kb = 0; kb < 8; ++kb) {
            const int kbase = k0 + kb * 16;
            const bool a0 = inA && (kbase <= qA_hi);   // wave-uniform
            const bool a1 = (kbase <= qB_hi);          // only binding on B's diagonal
            if (!a0 && !a1) continue;
            bf16x8 ak[2];
#pragma unroll
            for (int hh = 0; hh < 2; ++hh)
                ak[hh] = *(const bf16x8*)&Ks[buf][kb * 16 + l15][((hh * 4 + quad) ^ (l15 & 7)) * 8];

            f32x4 St[2] = {f32x4{0,0,0,0}, f32x4{0,0,0,0}};
            if (a0) {
#pragma unroll
                for (int hh = 0; hh < 2; ++hh)
                    St[0] = __builtin_amdgcn_mfma_f32_16x16x32_bf16(ak[hh], bq[0][hh], St[0], 0, 0, 0);
                if (diagA) {
#pragma unroll
                    for (int r = 0; r < 4; ++r)
                        if (kbase + quad * 4 + r > qrow0) St[0][r] = -1e30f;
                }
            }
            if (a1) {
#pragma unroll
                for (int hh = 0; hh < 2; ++hh)
                    St[1] = __builtin_amdgcn_mfma_f32_16x16x32_bf16(ak[hh], bq[1][hh], St[1], 0, 0, 0);
                if (diagB) {
#pragma unroll
                    for (int r = 0; r < 4; ++r)
                        if (kbase + quad * 4 + r > qrow1) St[1][r] = -1e30f;
                }
            }

            s16x4 ap[2];
#pragma unroll
            for (int qf = 0; qf < 2; ++qf) {
                float e0 = __builtin_amdgcn_exp2f(St[qf][0]);
                float e1 = __builtin_amdgcn_exp2f(St[qf][1]);
                float e2 = __builtin_amdgcn_exp2f(St[qf][2]);
                float e3 = __builtin_amdgcn_exp2f(St[qf][3]);
                uint2 uu;
                uu.x = pack2_fast(e0, e1);
                uu.y = pack2_fast(e2, e3);
                ap[qf] = *(s16x4*)&uu;
            }

            // PV: ctx += P @ V; l += P @ 1  (V frag shared by both Q frags)
#pragma unroll
            for (int db = 0; db < 4; ++db) {
                const int pg = (2 * kb + (quad >> 1)) ^ l15;
                s16x4 bv = *(const s16x4*)&Vs[buf][db * 16 + l15][pg * 8 + (quad & 1) * 4];
                if (a0) acc[0][db] = __builtin_amdgcn_mfma_f32_16x16x16bf16_1k(ap[0], bv, acc[0][db], 0, 0, 0);
                if (a1) acc[1][db] = __builtin_amdgcn_mfma_f32_16x16x16bf16_1k(ap[1], bv, acc[1][db], 0, 0, 0);
            }
            if (a0) accl[0] = __builtin_amdgcn_mfma_f32_16x16x16bf16_1k(ap[0], ones, accl[0], 0, 0, 0);
            if (a1) accl[1] = __builtin_amdgcn_mfma_f32_16x16x16bf16_1k(ap[1], ones, accl[1], 0, 0, 0);
        }

        __syncthreads();
    }

    // epilogue: pure in-lane — accl[qf][r] is l for query quad*4+r of frag qf
#pragma unroll
    for (int qf = 0; qf < 2; ++qf) {
        const int qb0 = (qf == 0) ? q0A : q0B;
#pragma unroll
        for (int r = 0; r < 4; ++r) {
            float ir = 1.0f / accl[qf][r];
            int gq = qb0 + wave * 16 + quad * 4 + r;
            size_t base = ((size_t)(b * SS + gq)) * DD + h * HD;
#pragma unroll
            for (int db = 0; db < 4; ++db)
                Ctxb[base + db * 16 + l15] = f2bf(acc[qf][db][r] * ir);
        }
    }
}

// ---------------- launcher ----------------
// Workspace (<= 48 MiB):
//   [0,8M)    Xb     bf16 [4096][1024]
//   [8M,14M)  Wqkvt  bf16 [3][1024][1024]   (W^T [n][k])
//   [14M,16M) Wot    bf16 [1024][1024]      (W^T)
//   [16M,24M) Qg     bf16 [32][2048][64]    (pre-scaled by log2e/8)
//   [24M,32M) Kg     bf16 [32][2048][64]
//   [32M,40M) Vt     bf16 [32][64][2048]    (transposed)
//   [40M,48M) Ctxb   bf16 [4096][1024]
extern "C" void kernel_launch(void* const* d_in, const int* in_sizes, int n_in,
                              void* d_out, int out_size, void* d_ws, size_t ws_size,
                              hipStream_t stream) {
    const float* x  = (const float*)d_in[0];
    const float* Wq = (const float*)d_in[1];
    const float* Wk = (const float*)d_in[2];
    const float* Wv = (const float*)d_in[3];
    const float* Wo = (const float*)d_in[4];
    const float* bo = (const float*)d_in[5];
    float* out = (float*)d_out;

    char* w = (char*)d_ws;
    unsigned short* Xb    = (unsigned short*)(w);
    unsigned short* Wqkvt = (unsigned short*)(w + (size_t)(8 << 20));
    unsigned short* Wot   = (unsigned short*)(w + (size_t)(14 << 20));
    unsigned short* Qg    = (unsigned short*)(w + (size_t)(16 << 20));
    unsigned short* Kg    = (unsigned short*)(w + (size_t)(24 << 20));
    unsigned short* Vt    = (unsigned short*)(w + (size_t)(32 << 20));
    unsigned short* Ctxb  = (unsigned short*)(w + (size_t)(40 << 20));

    prep_kernel<<<6144, 256, 0, stream>>>(x, Wq, Wk, Wv, Wo, Xb, Wqkvt, Wot);
    qkv_gemm_kernel<<<dim3(3 * DD / 128, MM / 128), 256, 0, stream>>>(Xb, Wqkvt, Qg, Kg, Vt);
    attn_kernel<<<dim3(BB * HH, 16), 256, 0, stream>>>(Qg, Kg, Vt, Ctxb);
    out_gemm_kernel<<<dim3(DD / 128, MM / 128), 256, 0, stream>>>(Ctxb, Wot, bo, out);
}

// Round 10
// 174.825 us; speedup vs baseline: 1.1853x; 1.1853x over previous
//
#include <hip/hip_runtime.h>

// Problem constants: B=2, S=2048, D=1024, H=16, HD=64
#define BB 2
#define SS 2048
#define DD 1024
#define HH 16
#define HD 64
#define MM (BB*SS)   // 4096 rows

typedef __bf16 bf16x8 __attribute__((ext_vector_type(8)));
typedef short  s16x4  __attribute__((ext_vector_type(4)));
typedef float  f32x4  __attribute__((ext_vector_type(4)));

#ifndef __has_builtin
#define __has_builtin(x) 0
#endif

__device__ __forceinline__ unsigned short f2bf(float f) {
    unsigned int u = __float_as_uint(f);
    u = (u + 0x7fffu + ((u >> 16) & 1u)) >> 16;  // RNE
    return (unsigned short)u;
}
__device__ __forceinline__ unsigned int pack2(float a, float b) {
    return (unsigned int)f2bf(a) | ((unsigned int)f2bf(b) << 16);
}
// fast pack (round-half-up): 2 adds + 1 v_perm
__device__ __forceinline__ unsigned int pack2_fast(float a, float b) {
#if __has_builtin(__builtin_amdgcn_perm)
    return __builtin_amdgcn_perm(__float_as_uint(b) + 0x8000u,
                                 __float_as_uint(a) + 0x8000u, 0x07060302u);
#else
    return ((__float_as_uint(a) + 0x8000u) >> 16) |
           ((__float_as_uint(b) + 0x8000u) & 0xffff0000u);
#endif
}

// async global->LDS, 16B per lane; LDS dest = wave-uniform base + lane*16
__device__ __forceinline__ void gload_lds16(const unsigned short* g, unsigned short* l) {
    __builtin_amdgcn_global_load_lds(
        (const __attribute__((address_space(1))) void*)g,
        (__attribute__((address_space(3))) void*)l, 16, 0, 0);
}

// ---------------- fused prep: cast x -> bf16, transpose W -> bf16 [n][k] ----------------
// blocks [0,2048): cast_x (8 elems/thread).
// blocks [2048,3072): W transpose, 64x64 tile/block, vectorized 16B stores.
__global__ __launch_bounds__(256) void prep_kernel(const float* __restrict__ x,
                                                   const float* __restrict__ Wq,
                                                   const float* __restrict__ Wk,
                                                   const float* __restrict__ Wv,
                                                   const float* __restrict__ Wo,
                                                   unsigned short* __restrict__ Xb,
                                                   unsigned short* __restrict__ Wqkvt,
                                                   unsigned short* __restrict__ Wot) {
    __shared__ float tile[64][65];
    const int bx = blockIdx.x;
    const int t = threadIdx.x;
    if (bx < 2048) {
        int gid = bx * 256 + t;
        int i = gid * 8;
        float4 a = *(const float4*)(x + i);
        float4 b = *(const float4*)(x + i + 4);
        uint4 o;
        o.x = pack2(a.x, a.y); o.y = pack2(a.z, a.w);
        o.z = pack2(b.x, b.y); o.w = pack2(b.z, b.w);
        ((uint4*)Xb)[gid] = o;
        return;
    }
    int pb = bx - 2048;                 // 0..1023
    int p = pb >> 8, rem = pb & 255;    // matrix, tile index
    int tn = rem & 15, tk = rem >> 4;   // 64-tiles in n and k
    const float* src = (p == 0) ? Wq : (p == 1) ? Wk : (p == 2) ? Wv : Wo;
    unsigned short* dst = (p == 3) ? Wot : (Wqkvt + (size_t)p * DD * DD);
    const int nn = t & 63, kk0 = t >> 6;
#pragma unroll
    for (int i = 0; i < 16; ++i) {
        int kk = kk0 + i * 4;
        tile[kk][nn] = src[(size_t)(tk * 64 + kk) * DD + tn * 64 + nn];
    }
    __syncthreads();
    const int nrow = t >> 2, kc = (t & 3) * 16;
    uint4 o0, o1;
    o0.x = pack2(tile[kc + 0][nrow],  tile[kc + 1][nrow]);
    o0.y = pack2(tile[kc + 2][nrow],  tile[kc + 3][nrow]);
    o0.z = pack2(tile[kc + 4][nrow],  tile[kc + 5][nrow]);
    o0.w = pack2(tile[kc + 6][nrow],  tile[kc + 7][nrow]);
    o1.x = pack2(tile[kc + 8][nrow],  tile[kc + 9][nrow]);
    o1.y = pack2(tile[kc + 10][nrow], tile[kc + 11][nrow]);
    o1.z = pack2(tile[kc + 12][nrow], tile[kc + 13][nrow]);
    o1.w = pack2(tile[kc + 14][nrow], tile[kc + 15][nrow]);
    unsigned short* dptr = dst + (size_t)(tn * 64 + nrow) * DD + tk * 64 + kc;
    *(uint4*)(dptr) = o0;
    *(uint4*)(dptr + 8) = o1;
}

// ============ 128x128-tile GEMM K-loop, global_load_lds staging, xor-swizzled ============
#define GEMM_K_LOOP(Aglob, Bglob)                                                 \
    __shared__ unsigned short smem[128 * 132];                                    \
    unsigned short (*As)[64]  = (unsigned short(*)[64])smem;                      \
    unsigned short (*Bs)[64]  = (unsigned short(*)[64])(smem + 128 * 64);         \
    unsigned short (*Es)[132] = (unsigned short(*)[132])smem;                     \
    const int n0 = blockIdx.x * 128, m0 = blockIdx.y * 128;                       \
    const int t = threadIdx.x;                                                    \
    const int wave = t >> 6, lane = t & 63;                                       \
    const int wm = wave >> 1, wn = wave & 1;                                      \
    const int l15 = lane & 15, quad = lane >> 4;                                  \
    const int lr = lane >> 3, lg = (lane & 7);                                    \
    const int lc = (lg ^ lr) * 8;   /* swizzled source granule */                 \
    f32x4 acc[4][4];                                                              \
    _Pragma("unroll") for (int i = 0; i < 4; ++i)                                 \
        _Pragma("unroll") for (int j = 0; j < 4; ++j) acc[i][j] = f32x4{0,0,0,0}; \
    for (int kt = 0; kt < 16; ++kt) {                                             \
        if (kt) __syncthreads();                                                  \
        _Pragma("unroll") for (int i = 0; i < 4; ++i) {                           \
            int row = wave * 32 + i * 8;                                          \
            gload_lds16(Aglob + (size_t)(m0 + row + lr) * DD + kt * 64 + lc, &As[row][0]); \
            gload_lds16(Bglob + (size_t)(n0 + row + lr) * DD + kt * 64 + lc, &Bs[row][0]); \
        }                                                                         \
        __syncthreads();                                                          \
        _Pragma("unroll") for (int kh = 0; kh < 2; ++kh) {                        \
            bf16x8 af[4], bfr[4];                                                 \
            _Pragma("unroll") for (int s = 0; s < 4; ++s)                         \
                af[s] = *(const bf16x8*)&As[wm * 64 + s * 16 + l15][((kh * 4 + quad) ^ (l15 & 7)) * 8]; \
            _Pragma("unroll") for (int s = 0; s < 4; ++s)                         \
                bfr[s] = *(const bf16x8*)&Bs[wn * 64 + s * 16 + l15][((kh * 4 + quad) ^ (l15 & 7)) * 8]; \
            _Pragma("unroll") for (int i = 0; i < 4; ++i)                         \
                _Pragma("unroll") for (int j = 0; j < 4; ++j)                     \
                    acc[i][j] = __builtin_amdgcn_mfma_f32_16x16x32_bf16(af[i], bfr[j], acc[i][j], 0, 0, 0); \
        }                                                                         \
    }                                                                             \
    __syncthreads();   /* K-loop done; smem reusable */

// ---------------- QKV fused GEMM; LDS-transpose epilogue; Q pre-scaled ----------------
__global__ __launch_bounds__(256) void qkv_gemm_kernel(const unsigned short* __restrict__ Xb,
                                                       const unsigned short* __restrict__ Wt,
                                                       unsigned short* __restrict__ Qg,
                                                       unsigned short* __restrict__ Kg,
                                                       unsigned short* __restrict__ Vt) {
    GEMM_K_LOOP(Xb, Wt)
    const int p = n0 >> 10;   // projection uniform per block
    const float qs = (p == 0) ? 0.18033688011112042f : 1.0f;  // log2(e)/sqrt(HD) folded into Q
    if (p < 2) {
#pragma unroll
        for (int sm = 0; sm < 4; ++sm)
#pragma unroll
            for (int sn = 0; sn < 4; ++sn)
#pragma unroll
                for (int i = 0; i < 4; ++i)
                    Es[wm * 64 + sm * 16 + quad * 4 + i][wn * 64 + sn * 16 + l15] = f2bf(acc[sm][sn][i] * qs);
    } else {
#pragma unroll
        for (int sm = 0; sm < 4; ++sm)
#pragma unroll
            for (int sn = 0; sn < 4; ++sn)
#pragma unroll
                for (int i = 0; i < 4; ++i)
                    Es[wn * 64 + sn * 16 + l15][wm * 64 + sm * 16 + quad * 4 + i] = f2bf(acc[sm][sn][i]);
    }
    __syncthreads();
    const int h0 = (n0 & 1023) >> 6;
    if (p < 2) {
        unsigned short* dst0 = p ? Kg : Qg;
        int ml = t >> 1, seg = t & 1;
        int gm = m0 + ml, b = gm >> 11, s = gm & 2047;
        unsigned short* dptr = dst0 + ((size_t)(b * HH + h0 + seg) * SS + s) * HD;
#pragma unroll
        for (int j = 0; j < 8; ++j)
            *(uint4*)(dptr + j * 8) = *(const uint4*)&Es[ml][seg * 64 + j * 8];
    } else {
        int nl = t >> 1, mh = t & 1;
        int h = h0 + (nl >> 6), hd = nl & 63;
        int b = m0 >> 11, s0 = (m0 & 2047) + mh * 64;
        unsigned short* dptr = Vt + ((size_t)(b * HH + h) * HD + hd) * SS + s0;
#pragma unroll
        for (int j = 0; j < 8; ++j)
            *(uint4*)(dptr + j * 8) = *(const uint4*)&Es[nl][mh * 64 + j * 8];
    }
}

// ---------------- Output projection: out = Ctx @ Wo + bo (fp32 out) ----------------
__global__ __launch_bounds__(256) void out_gemm_kernel(const unsigned short* __restrict__ Ctxb,
                                                       const unsigned short* __restrict__ Wot,
                                                       const float* __restrict__ bo,
                                                       float* __restrict__ out) {
    GEMM_K_LOOP(Ctxb, Wot)
    (void)Es;
#pragma unroll
    for (int sn = 0; sn < 4; ++sn) {
        int gn = n0 + wn * 64 + sn * 16 + l15;
        float bias = bo[gn];
#pragma unroll
        for (int sm = 0; sm < 4; ++sm)
#pragma unroll
            for (int i = 0; i < 4; ++i) {
                int gm = m0 + wm * 64 + sm * 16 + quad * 4 + i;
                out[(size_t)gm * DD + gn] = acc[sm][sn][i] + bias;
            }
    }
}

// ---------------- MFMA flash attention, causal, two-phase balanced pairing ----------------
// Block = (bh, pi): q-tiles A=pi, B=31-pi (64 queries each), ONE shared 128-key stream.
// Phase 1 (kt<aIters): both frags, branch-free body; fully-masked A chunks rely on
// exp2(-1e30)=0. Phase 2: frag-B only (lean body, no wasted exp). Work per block
// = aIters + bIters ~ 17 (uniform); grid 512 = 2/CU all-resident, no drain tail.
// l via ones-MFMA (in-lane epilogue). xor-swizzled LDS granules.
__global__ __launch_bounds__(256) void attn_kernel(const unsigned short* __restrict__ Qg,
                                                   const unsigned short* __restrict__ Kg,
                                                   const unsigned short* __restrict__ Vt,
                                                   unsigned short* __restrict__ Ctxb) {
    __shared__ unsigned short Ks[2][128][64];
    __shared__ unsigned short Vs[2][64][128];

    const int bh = blockIdx.x;
    const int pi = blockIdx.y;           // pair index 0..15
    const int t = threadIdx.x;
    const int wave = t >> 6, lane = t & 63;
    const int l15 = lane & 15, quad = lane >> 4;
    const int q0A = pi * 64;
    const int q0B = (31 - pi) * 64;
    const int aIters = (pi + 2) >> 1;          // ceil((pi+1)/2)
    const int bIters = (33 - pi) >> 1;         // ceil((32-pi)/2)
    const int b = bh >> 4, h = bh & 15;

    const unsigned short* Qb = Qg + (size_t)bh * SS * HD;
    const unsigned short* Kb = Kg + (size_t)bh * SS * HD;
    const unsigned short* Vb = Vt + (size_t)bh * HD * SS;

    const int qrow0 = q0A + wave * 16 + l15;
    const int qrow1 = q0B + wave * 16 + l15;
    bf16x8 bq[2][2];
#pragma unroll
    for (int hh = 0; hh < 2; ++hh) {
        bq[0][hh] = *(const bf16x8*)(Qb + (size_t)qrow0 * HD + hh * 32 + quad * 8);
        bq[1][hh] = *(const bf16x8*)(Qb + (size_t)qrow1 * HD + hh * 32 + quad * 8);
    }

    // DMA lane decomposition + swizzled source addresses
    const int rloc = lane >> 3, pcl = lane & 7;   // K: 8 rows x 8 granules (16B)
    const int vrl = lane >> 4, vgc = lane & 15;   // V: 4 rows x 16 granules (16B)
    const unsigned short* ksrc[4];
    const unsigned short* vsrc[4];
#pragma unroll
    for (int j = 0; j < 4; ++j) {
        int krow = (wave * 4 + j) * 8 + rloc;
        ksrc[j] = Kb + (size_t)krow * HD + (pcl ^ rloc) * 8;
        int vrow = wave * 16 + j * 4 + vrl;
        vsrc[j] = Vb + (size_t)vrow * SS + (vgc ^ (vrow & 15)) * 8;
    }

    f32x4 acc[2][4];
#pragma unroll
    for (int qf = 0; qf < 2; ++qf)
#pragma unroll
        for (int db = 0; db < 4; ++db) acc[qf][db] = f32x4{0,0,0,0};
    f32x4 accl[2] = {f32x4{0,0,0,0}, f32x4{0,0,0,0}};
    const s16x4 ones = {(short)0x3F80, (short)0x3F80, (short)0x3F80, (short)0x3F80};

    // prologue: tile 0 -> buf 0
#pragma unroll
    for (int j = 0; j < 4; ++j) {
        gload_lds16(ksrc[j], &Ks[0][(wave * 4 + j) * 8][0]);
        gload_lds16(vsrc[j], &Vs[0][wave * 16 + j * 4][0]);
    }
    __syncthreads();

    // ---- Phase 1: kt in [0, aIters) — BOTH fragments active ----
    for (int kt = 0; kt < aIters; ++kt) {
        const int buf = kt & 1;
        const int k0 = kt * 128;
        if (kt + 1 < bIters) {
            const int nb = buf ^ 1;
#pragma unroll
            for (int j = 0; j < 4; ++j) {
                gload_lds16(ksrc[j] + (size_t)(kt + 1) * 128 * HD, &Ks[nb][(wave * 4 + j) * 8][0]);
                gload_lds16(vsrc[j] + (kt + 1) * 128,              &Vs[nb][wave * 16 + j * 4][0]);
            }
        }
        const bool diagA = (kt == aIters - 1);
#pragma unroll
        for (int kb = 0; kb < 8; ++kb) {
            const int kbase = k0 + kb * 16;
            bf16x8 ak[2];
#pragma unroll
            for (int hh = 0; hh < 2; ++hh)
                ak[hh] = *(const bf16x8*)&Ks[buf][kb * 16 + l15][((hh * 4 + quad) ^ (l15 & 7)) * 8];
            f32x4 St[2] = {f32x4{0,0,0,0}, f32x4{0,0,0,0}};
#pragma unroll
            for (int hh = 0; hh < 2; ++hh) {
                St[0] = __builtin_amdgcn_mfma_f32_16x16x32_bf16(ak[hh], bq[0][hh], St[0], 0, 0, 0);
                St[1] = __builtin_amdgcn_mfma_f32_16x16x32_bf16(ak[hh], bq[1][hh], St[1], 0, 0, 0);
            }
            if (diagA) {   // causal mask for A only (B's bound can't bind in phase 1)
#pragma unroll
                for (int r = 0; r < 4; ++r)
                    if (kbase + quad * 4 + r > qrow0) St[0][r] = -1e30f;
            }
            s16x4 ap[2];
#pragma unroll
            for (int qf = 0; qf < 2; ++qf) {
                float e0 = __builtin_amdgcn_exp2f(St[qf][0]);
                float e1 = __builtin_amdgcn_exp2f(St[qf][1]);
                float e2 = __builtin_amdgcn_exp2f(St[qf][2]);
                float e3 = __builtin_amdgcn_exp2f(St[qf][3]);
                uint2 uu;
                uu.x = pack2_fast(e0, e1);
                uu.y = pack2_fast(e2, e3);
                ap[qf] = *(s16x4*)&uu;
            }
#pragma unroll
            for (int db = 0; db < 4; ++db) {
                const int pg = (2 * kb + (quad >> 1)) ^ l15;
                s16x4 bv = *(const s16x4*)&Vs[buf][db * 16 + l15][pg * 8 + (quad & 1) * 4];
                acc[0][db] = __builtin_amdgcn_mfma_f32_16x16x16bf16_1k(ap[0], bv, acc[0][db], 0, 0, 0);
                acc[1][db] = __builtin_amdgcn_mfma_f32_16x16x16bf16_1k(ap[1], bv, acc[1][db], 0, 0, 0);
            }
            accl[0] = __builtin_amdgcn_mfma_f32_16x16x16bf16_1k(ap[0], ones, accl[0], 0, 0, 0);
            accl[1] = __builtin_amdgcn_mfma_f32_16x16x16bf16_1k(ap[1], ones, accl[1], 0, 0, 0);
        }
        __syncthreads();
    }

    // ---- Phase 2: kt in [aIters, bIters) — fragment B only ----
    for (int kt = aIters; kt < bIters; ++kt) {
        const int buf = kt & 1;
        const int k0 = kt * 128;
        if (kt + 1 < bIters) {
            const int nb = buf ^ 1;
#pragma unroll
            for (int j = 0; j < 4; ++j) {
                gload_lds16(ksrc[j] + (size_t)(kt + 1) * 128 * HD, &Ks[nb][(wave * 4 + j) * 8][0]);
                gload_lds16(vsrc[j] + (kt + 1) * 128,              &Vs[nb][wave * 16 + j * 4][0]);
            }
        }
        const bool diagB = (kt == bIters - 1);
#pragma unroll
        for (int kb = 0; kb < 8; ++kb) {
            const int kbase = k0 + kb * 16;
            f32x4 St = f32x4{0, 0, 0, 0};
#pragma unroll
            for (int hh = 0; hh < 2; ++hh) {
                bf16x8 ak = *(const bf16x8*)&Ks[buf][kb * 16 + l15][((hh * 4 + quad) ^ (l15 & 7)) * 8];
                St = __builtin_amdgcn_mfma_f32_16x16x32_bf16(ak, bq[1][hh], St, 0, 0, 0);
            }
            if (diagB) {
#pragma unroll
                for (int r = 0; r < 4; ++r)
                    if (kbase + quad * 4 + r > qrow1) St[r] = -1e30f;
            }
            float e0 = __builtin_amdgcn_exp2f(St[0]);
            float e1 = __builtin_amdgcn_exp2f(St[1]);
            float e2 = __builtin_amdgcn_exp2f(St[2]);
            float e3 = __builtin_amdgcn_exp2f(St[3]);
            uint2 uu;
            uu.x = pack2_fast(e0, e1);
            uu.y = pack2_fast(e2, e3);
            s16x4 ap = *(s16x4*)&uu;
#pragma unroll
            for (int db = 0; db < 4; ++db) {
                const int pg = (2 * kb + (quad >> 1)) ^ l15;
                s16x4 bv = *(const s16x4*)&Vs[buf][db * 16 + l15][pg * 8 + (quad & 1) * 4];
                acc[1][db] = __builtin_amdgcn_mfma_f32_16x16x16bf16_1k(ap, bv, acc[1][db], 0, 0, 0);
            }
            accl[1] = __builtin_amdgcn_mfma_f32_16x16x16bf16_1k(ap, ones, accl[1], 0, 0, 0);
        }
        __syncthreads();
    }

    // epilogue: pure in-lane — accl[qf][r] is l for query quad*4+r of frag qf
#pragma unroll
    for (int qf = 0; qf < 2; ++qf) {
        const int qb0 = (qf == 0) ? q0A : q0B;
#pragma unroll
        for (int r = 0; r < 4; ++r) {
            float ir = 1.0f / accl[qf][r];
            int gq = qb0 + wave * 16 + quad * 4 + r;
            size_t base = ((size_t)(b * SS + gq)) * DD + h * HD;
#pragma unroll
            for (int db = 0; db < 4; ++db)
                Ctxb[base + db * 16 + l15] = f2bf(acc[qf][db][r] * ir);
        }
    }
}

// ---------------- launcher ----------------
// Workspace (<= 48 MiB):
//   [0,8M)    Xb     bf16 [4096][1024]
//   [8M,14M)  Wqkvt  bf16 [3][1024][1024]   (W^T [n][k])
//   [14M,16M) Wot    bf16 [1024][1024]      (W^T)
//   [16M,24M) Qg     bf16 [32][2048][64]    (pre-scaled by log2e/8)
//   [24M,32M) Kg     bf16 [32][2048][64]
//   [32M,40M) Vt     bf16 [32][64][2048]    (transposed)
//   [40M,48M) Ctxb   bf16 [4096][1024]
extern "C" void kernel_launch(void* const* d_in, const int* in_sizes, int n_in,
                              void* d_out, int out_size, void* d_ws, size_t ws_size,
                              hipStream_t stream) {
    const float* x  = (const float*)d_in[0];
    const float* Wq = (const float*)d_in[1];
    const float* Wk = (const float*)d_in[2];
    const float* Wv = (const float*)d_in[3];
    const float* Wo = (const float*)d_in[4];
    const float* bo = (const float*)d_in[5];
    float* out = (float*)d_out;

    char* w = (char*)d_ws;
    unsigned short* Xb    = (unsigned short*)(w);
    unsigned short* Wqkvt = (unsigned short*)(w + (size_t)(8 << 20));
    unsigned short* Wot   = (unsigned short*)(w + (size_t)(14 << 20));
    unsigned short* Qg    = (unsigned short*)(w + (size_t)(16 << 20));
    unsigned short* Kg    = (unsigned short*)(w + (size_t)(24 << 20));
    unsigned short* Vt    = (unsigned short*)(w + (size_t)(32 << 20));
    unsigned short* Ctxb  = (unsigned short*)(w + (size_t)(40 << 20));

    prep_kernel<<<3072, 256, 0, stream>>>(x, Wq, Wk, Wv, Wo, Xb, Wqkvt, Wot);
    qkv_gemm_kernel<<<dim3(3 * DD / 128, MM / 128), 256, 0, stream>>>(Xb, Wqkvt, Qg, Kg, Vt);
    attn_kernel<<<dim3(BB * HH, 16), 256, 0, stream>>>(Qg, Kg, Vt, Ctxb);
    out_gemm_kernel<<<dim3(DD / 128, MM / 128), 256, 0, stream>>>(Ctxb, Wot, bo, out);
}